// Round 7
// baseline (193.834 us; speedup 1.0000x reference)
//
#include <hip/hip_runtime.h>

typedef unsigned short u16;
typedef __bf16 bf16x8 __attribute__((ext_vector_type(8)));
typedef short s16x4 __attribute__((ext_vector_type(4)));
typedef float f32x4 __attribute__((ext_vector_type(4)));

__device__ __forceinline__ unsigned f2u(float f) { union { float f; unsigned u; } v; v.f = f; return v.u; }
__device__ __forceinline__ float u2f(unsigned u) { union { unsigned u; float f; } v; v.u = u; return v.f; }

__device__ __forceinline__ u16 f32_to_bf16(float f) {
  unsigned u = f2u(f);
  return (u16)((u + 0x7FFFu + ((u >> 16) & 1u)) >> 16);
}
__device__ __forceinline__ unsigned pack_rnd(float a, float b) {
  unsigned ra = f2u(a), rb = f2u(b);
  ra = ra + 0x7FFFu + ((ra >> 16) & 1u);
  rb = (rb + 0x7FFFu + ((rb >> 16) & 1u)) & 0xFFFF0000u;
  return (ra >> 16) | rb;
}
__device__ __forceinline__ unsigned pack_trunc(float a, float b) {
#if __has_builtin(__builtin_amdgcn_perm)
  return __builtin_amdgcn_perm(f2u(b), f2u(a), 0x07060302u);
#else
  return (f2u(a) >> 16) | (f2u(b) & 0xFFFF0000u);
#endif
}
__device__ __forceinline__ unsigned perm_lo(unsigned a, unsigned b) {
#if __has_builtin(__builtin_amdgcn_perm)
  return __builtin_amdgcn_perm(b, a, 0x05040100u);
#else
  return (a & 0xFFFFu) | (b << 16);
#endif
}
__device__ __forceinline__ unsigned perm_hi(unsigned a, unsigned b) {
#if __has_builtin(__builtin_amdgcn_perm)
  return __builtin_amdgcn_perm(b, a, 0x07060302u);
#else
  return (a >> 16) | (b & 0xFFFF0000u);
#endif
}

// async global->LDS, 16B per lane. LDS dest = wave-uniform base + lane*16.
#if __has_builtin(__builtin_amdgcn_global_load_lds)
#define ASYNC_CP 1
typedef __attribute__((address_space(1))) const unsigned gu32;
typedef __attribute__((address_space(3))) unsigned lu32;
__device__ __forceinline__ void gl_lds16(const u16* g, u16* l) {
  __builtin_amdgcn_global_load_lds((gu32*)g, (lu32*)l, 16, 0, 0);
}
#else
#define ASYNC_CP 0
#endif

// ---------------------------------------------------------------------------
// prep: blocks [0,4096) = LayerNorm rows; blocks [4096,4736) = weight
// transpose+cvt tiles (w_q 256, w_k 64, w_v 64, w_o 256).
// ---------------------------------------------------------------------------
__global__ __launch_bounds__(256) void prep_kernel(
    const float* __restrict__ x, const float* __restrict__ gamma,
    const float* __restrict__ beta, u16* __restrict__ xn,
    const float* __restrict__ w_q, const float* __restrict__ w_k,
    const float* __restrict__ w_v, const float* __restrict__ w_o,
    u16* __restrict__ wqkvT, u16* __restrict__ woT) {
  __shared__ float tile[64][65];
  int t = threadIdx.x;
  int bid = blockIdx.x;
  if (bid < 4096) {
    int row = bid;
    const float4 v = ((const float4*)(x + (size_t)row * 1024))[t];
    float s = v.x + v.y + v.z + v.w;
    float ss = v.x * v.x + v.y * v.y + v.z * v.z + v.w * v.w;
#pragma unroll
    for (int m = 1; m < 64; m <<= 1) {
      s += __shfl_xor(s, m, 64);
      ss += __shfl_xor(ss, m, 64);
    }
    __shared__ float as_[4], ass[4];
    int wave = t >> 6;
    if ((t & 63) == 0) { as_[wave] = s; ass[wave] = ss; }
    __syncthreads();
    s = as_[0] + as_[1] + as_[2] + as_[3];
    ss = ass[0] + ass[1] + ass[2] + ass[3];
    float mu = s * (1.0f / 1024.0f);
    float var = ss * (1.0f / 1024.0f) - mu * mu;
    float rstd = rsqrtf(var + 1e-5f);
    float4 g = ((const float4*)gamma)[t];
    float4 b = ((const float4*)beta)[t];
    uint2 o;
    o.x = pack_rnd((v.x - mu) * rstd * g.x + b.x, (v.y - mu) * rstd * g.y + b.y);
    o.y = pack_rnd((v.z - mu) * rstd * g.z + b.z, (v.w - mu) * rstd * g.w + b.w);
    ((uint2*)(xn + (size_t)row * 1024))[t] = o;
    return;
  }
  int idx = bid - 4096;
  const float* src; u16* dst; int N, n0, k0;
  if (idx < 256) {
    src = w_q; dst = wqkvT; N = 1024; n0 = (idx & 15) * 64; k0 = (idx >> 4) * 64;
  } else if (idx < 320) {
    int i = idx - 256;
    src = w_k; dst = wqkvT + 1024 * 1024; N = 256; n0 = (i & 3) * 64; k0 = (i >> 2) * 64;
  } else if (idx < 384) {
    int i = idx - 320;
    src = w_v; dst = wqkvT + 1280 * 1024; N = 256; n0 = (i & 3) * 64; k0 = (i >> 2) * 64;
  } else {
    int i = idx - 384;
    src = w_o; dst = woT; N = 1024; n0 = (i & 15) * 64; k0 = (i >> 4) * 64;
  }
  const int K = 1024;
  int c = t & 63, r4 = t >> 6;
#pragma unroll
  for (int rr = r4; rr < 64; rr += 4)
    tile[rr][c] = src[(size_t)(k0 + rr) * N + n0 + c];
  __syncthreads();
#pragma unroll
  for (int rr = r4; rr < 64; rr += 4)
    dst[(size_t)(n0 + rr) * K + k0 + c] = f32_to_bf16(tile[c][rr]);
}

// ---------------------------------------------------------------------------
// GEMM1: qkv[M][1536] = xn[M][1024] @ wqkvT^T, Q cols pre-scaled.
// BM=64, BN=128, BK=64; 256 threads (4 waves 2x2), wave = 32x64 via 2x4 MFMA.
// ---------------------------------------------------------------------------
__global__ __launch_bounds__(256) void gemm_qkv_kernel(
    const u16* __restrict__ A, const u16* __restrict__ Bt,
    u16* __restrict__ Cv, int M, int N, int K, int ldc,
    float qscale, int qcols) {
  __shared__ __align__(16) u16 sA[64 * 64];
  __shared__ __align__(16) u16 sB[128 * 64];
  int t = threadIdx.x;
  int m0 = blockIdx.y * 64, n0 = blockIdx.x * 128;
  int wave = t >> 6, lane = t & 63;
  int wm = wave >> 1, wn = wave & 1;
  int l15 = lane & 15, quad = lane >> 4;

  f32x4 acc[2][4];
#pragma unroll
  for (int i = 0; i < 2; i++)
#pragma unroll
    for (int j = 0; j < 4; j++) acc[i][j] = f32x4{0.f, 0.f, 0.f, 0.f};

  int arow = wave * 8 + (lane >> 3);
  int achk = (lane & 7) * 8;
  const u16* Ap = A + (size_t)(m0 + arow) * K + achk;
  const u16* Bp = Bt + (size_t)(n0 + arow) * K + achk;
  u16* sAw = &sA[(wave * 8) * 64];
  u16* sBw = &sB[(wave * 8) * 64];

  for (int k0 = 0; k0 < K; k0 += 64) {
#if ASYNC_CP
    __syncthreads();
    gl_lds16(Ap + k0, sAw);
    gl_lds16(Ap + k0 + (size_t)32 * K, sAw + 32 * 64);
    gl_lds16(Bp + k0, sBw);
    gl_lds16(Bp + k0 + (size_t)32 * K, sBw + 32 * 64);
    gl_lds16(Bp + k0 + (size_t)64 * K, sBw + 64 * 64);
    gl_lds16(Bp + k0 + (size_t)96 * K, sBw + 96 * 64);
    __syncthreads();
#else
    uint4 av0 = *(const uint4*)(Ap + k0);
    uint4 av1 = *(const uint4*)(Ap + k0 + (size_t)32 * K);
    uint4 bv0 = *(const uint4*)(Bp + k0);
    uint4 bv1 = *(const uint4*)(Bp + k0 + (size_t)32 * K);
    uint4 bv2 = *(const uint4*)(Bp + k0 + (size_t)64 * K);
    uint4 bv3 = *(const uint4*)(Bp + k0 + (size_t)96 * K);
    __syncthreads();
    *(uint4*)&sA[arow * 64 + achk] = av0;
    *(uint4*)&sA[(arow + 32) * 64 + achk] = av1;
    *(uint4*)&sB[arow * 64 + achk] = bv0;
    *(uint4*)&sB[(arow + 32) * 64 + achk] = bv1;
    *(uint4*)&sB[(arow + 64) * 64 + achk] = bv2;
    *(uint4*)&sB[(arow + 96) * 64 + achk] = bv3;
    __syncthreads();
#endif
#pragma unroll
    for (int ks = 0; ks < 2; ++ks) {
      bf16x8 af[2], bf[4];
#pragma unroll
      for (int mi = 0; mi < 2; mi++)
        af[mi] = *(const bf16x8*)&sA[(wm * 32 + mi * 16 + l15) * 64 + ks * 32 + quad * 8];
#pragma unroll
      for (int ni = 0; ni < 4; ni++)
        bf[ni] = *(const bf16x8*)&sB[(wn * 64 + ni * 16 + l15) * 64 + ks * 32 + quad * 8];
#pragma unroll
      for (int mi = 0; mi < 2; mi++)
#pragma unroll
        for (int ni = 0; ni < 4; ni++)
          acc[mi][ni] = __builtin_amdgcn_mfma_f32_16x16x32_bf16(
              af[mi], bf[ni], acc[mi][ni], 0, 0, 0);
    }
  }
#pragma unroll
  for (int mi = 0; mi < 2; mi++)
#pragma unroll
    for (int ni = 0; ni < 4; ni++) {
      int row = m0 + wm * 32 + mi * 16 + quad * 4;
      int col = n0 + wn * 64 + ni * 16 + l15;
      float sc = (col < qcols) ? qscale : 1.0f;
#pragma unroll
      for (int rr = 0; rr < 4; rr++)
        Cv[(size_t)(row + rr) * ldc + col] = f32_to_bf16(acc[mi][ni][rr] * sc);
    }
}

// ---------------------------------------------------------------------------
// GQA flash attention (r4 version, verified 57us). Key-split partials.
// ---------------------------------------------------------------------------
__global__ __launch_bounds__(256) void attn_kernel(
    const u16* __restrict__ qkv, u16* __restrict__ oP0, u16* __restrict__ oP1,
    float* __restrict__ lP0, float* __restrict__ lP1) {
  const int LD = 1536;
  int qt = blockIdx.x;   // 0..7
  int bh = blockIdx.y;   // 0..31
  int kz = blockIdx.z;   // 0..1
  int b = bh >> 4, h = bh & 15, g = h >> 2;
  u16* oP = kz ? oP1 : oP0;
  float* lP = kz ? lP1 : lP0;

  __shared__ __align__(16) u16 sK[64 * 72];  // [key][d]
  __shared__ __align__(16) u16 sV[64 * 72];  // [d][key] transposed

  int t = threadIdx.x, wave = t >> 6, lane = t & 63;
  int l15 = lane & 15, quad = lane >> 4;

  const u16* qbase = qkv + (size_t)(b * 2048 + qt * 256 + wave * 64) * LD + h * 64;
  const u16* kbase = qkv + (size_t)(b * 2048 + kz * 1024) * LD + 1024 + g * 64;
  const u16* vbase = kbase + 256;

  bf16x8 qf[4][2];
#pragma unroll
  for (int qs = 0; qs < 4; ++qs)
#pragma unroll
    for (int ks = 0; ks < 2; ++ks)
      qf[qs][ks] = *(const bf16x8*)(qbase + (size_t)(qs * 16 + l15) * LD + ks * 32 + quad * 8);

  f32x4 oacc[4][4];
  f32x4 lacc[4];
#pragma unroll
  for (int qs = 0; qs < 4; ++qs) {
    lacc[qs] = f32x4{0.f, 0.f, 0.f, 0.f};
#pragma unroll
    for (int md = 0; md < 4; ++md) oacc[qs][md] = f32x4{0.f, 0.f, 0.f, 0.f};
  }

  const s16x4 ones = {(short)0x3F80, (short)0x3F80, (short)0x3F80, (short)0x3F80};
  const f32x4 fzero = {0.f, 0.f, 0.f, 0.f};

  int sr = t >> 3, sq = t & 7;
  int vkp = (t & 31) * 2, vdc = (t >> 5) * 8;

  uint4 ka0, ka1, va0, va1;
  {
    const u16* kp0 = kbase + (size_t)sr * LD + sq * 8;
    ka0 = *(const uint4*)kp0;
    ka1 = *(const uint4*)(kp0 + (size_t)32 * LD);
    const u16* vp0 = vbase + (size_t)vkp * LD + vdc;
    va0 = *(const uint4*)vp0;
    va1 = *(const uint4*)(vp0 + LD);
  }

  for (int kt = 0; kt < 16; ++kt) {
    __syncthreads();
    *(uint4*)&sK[sr * 72 + sq * 8] = ka0;
    *(uint4*)&sK[(sr + 32) * 72 + sq * 8] = ka1;
    {
      const unsigned* aw = (const unsigned*)&va0;
      const unsigned* bw = (const unsigned*)&va1;
#pragma unroll
      for (int w = 0; w < 4; ++w) {
        *(unsigned*)&sV[(vdc + 2 * w) * 72 + vkp] = perm_lo(aw[w], bw[w]);
        *(unsigned*)&sV[(vdc + 2 * w + 1) * 72 + vkp] = perm_hi(aw[w], bw[w]);
      }
    }
    __syncthreads();

    if (kt < 15) {
      const u16* kp0 = kbase + (size_t)((kt + 1) * 64 + sr) * LD + sq * 8;
      ka0 = *(const uint4*)kp0;
      ka1 = *(const uint4*)(kp0 + (size_t)32 * LD);
      const u16* vp0 = vbase + (size_t)((kt + 1) * 64 + vkp) * LD + vdc;
      va0 = *(const uint4*)vp0;
      va1 = *(const uint4*)(vp0 + LD);
    }

    s16x4 pf[4][4];
#pragma unroll
    for (int ni = 0; ni < 4; ++ni) {
      bf16x8 kf0 = *(const bf16x8*)&sK[(ni * 16 + l15) * 72 + quad * 8];
      bf16x8 kf1 = *(const bf16x8*)&sK[(ni * 16 + l15) * 72 + 32 + quad * 8];
      f32x4 sacc[4];
#pragma unroll
      for (int qs = 0; qs < 4; ++qs)
        sacc[qs] = __builtin_amdgcn_mfma_f32_16x16x32_bf16(kf0, qf[qs][0], fzero, 0, 0, 0);
#pragma unroll
      for (int qs = 0; qs < 4; ++qs)
        sacc[qs] = __builtin_amdgcn_mfma_f32_16x16x32_bf16(kf1, qf[qs][1], sacc[qs], 0, 0, 0);
#pragma unroll
      for (int qs = 0; qs < 4; ++qs) {
        float p0 = __builtin_amdgcn_exp2f(sacc[qs][0]);
        float p1 = __builtin_amdgcn_exp2f(sacc[qs][1]);
        float p2 = __builtin_amdgcn_exp2f(sacc[qs][2]);
        float p3 = __builtin_amdgcn_exp2f(sacc[qs][3]);
        uint2 pk;
        pk.x = pack_trunc(p0, p1);
        pk.y = pack_trunc(p2, p3);
        pf[qs][ni] = *(s16x4*)&pk;
        lacc[qs] = __builtin_amdgcn_mfma_f32_16x16x16bf16_1k(ones, pf[qs][ni], lacc[qs], 0, 0, 0);
      }
    }

#pragma unroll
    for (int md = 0; md < 4; ++md)
#pragma unroll
      for (int ni = 0; ni < 4; ++ni) {
        s16x4 vf = *(const s16x4*)&sV[(md * 16 + l15) * 72 + ni * 16 + quad * 4];
#pragma unroll
        for (int qs = 0; qs < 4; ++qs)
          oacc[qs][md] = __builtin_amdgcn_mfma_f32_16x16x16bf16_1k(vf, pf[qs][ni], oacc[qs][md], 0, 0, 0);
      }
  }

#pragma unroll
  for (int qs = 0; qs < 4; ++qs) {
    int row = b * 2048 + qt * 256 + wave * 64 + qs * 16 + l15;
    u16* ob = oP + (size_t)row * 1024 + h * 64 + quad * 4;
#pragma unroll
    for (int md = 0; md < 4; ++md) {
      uint2 o;
      o.x = pack_rnd(oacc[qs][md][0], oacc[qs][md][1]);
      o.y = pack_rnd(oacc[qs][md][2], oacc[qs][md][3]);
      *(uint2*)(ob + md * 16) = o;
    }
    if (quad == 0) lP[row * 16 + h] = lacc[qs][0];
  }
}

// ---------------------------------------------------------------------------
// GEMM2 with fused combine: out[4096][1024] f32 = ((O0+O1)/lsum) @ woT^T + b.
// A-tile built on the fly from key-split partials during staging; h = k0/64
// is wave-uniform per K-iter. BM=64, BN=128; grid (8,64) = 512 blocks.
// ---------------------------------------------------------------------------
__global__ __launch_bounds__(256) void gemm_o_kernel(
    const u16* __restrict__ oP0, const u16* __restrict__ oP1,
    const float* __restrict__ lP0, const float* __restrict__ lP1,
    const u16* __restrict__ Bt, float* __restrict__ C,
    const float* __restrict__ bias) {
  const int K = 1024, ldc = 1024;
  __shared__ __align__(16) u16 sA[64 * 64];
  __shared__ __align__(16) u16 sB[128 * 64];
  int t = threadIdx.x;
  int m0 = blockIdx.y * 64, n0 = blockIdx.x * 128;
  int wave = t >> 6, lane = t & 63;
  int wm = wave >> 1, wn = wave & 1;
  int l15 = lane & 15, quad = lane >> 4;

  f32x4 acc[2][4];
#pragma unroll
  for (int i = 0; i < 2; i++)
#pragma unroll
    for (int j = 0; j < 4; j++) acc[i][j] = f32x4{0.f, 0.f, 0.f, 0.f};

  int arow = wave * 8 + (lane >> 3);
  int achk = (lane & 7) * 8;
  int row0 = m0 + arow, row1 = row0 + 32;
  const u16* Bp = Bt + (size_t)(n0 + arow) * K + achk;
  u16* sBw = &sB[(wave * 8) * 64];

  // prefetch iter-0 A partials + lsums
  uint4 pa0, pa1, pb0, pb1;
  float rin0, rin1;
  {
    size_t o0 = (size_t)row0 * 1024 + achk, o1 = (size_t)row1 * 1024 + achk;
    pa0 = *(const uint4*)(oP0 + o0);
    pb0 = *(const uint4*)(oP1 + o0);
    pa1 = *(const uint4*)(oP0 + o1);
    pb1 = *(const uint4*)(oP1 + o1);
    rin0 = 1.0f / (lP0[row0 * 16] + lP1[row0 * 16]);
    rin1 = 1.0f / (lP0[row1 * 16] + lP1[row1 * 16]);
  }

  for (int k0 = 0; k0 < K; k0 += 64) {
    // combine this iter's A partials in registers (pre-barrier, overlappable)
    uint4 w0, w1;
    {
      const unsigned* a0 = (const unsigned*)&pa0;
      const unsigned* b0 = (const unsigned*)&pb0;
      const unsigned* a1 = (const unsigned*)&pa1;
      const unsigned* b1 = (const unsigned*)&pb1;
      unsigned* o0 = (unsigned*)&w0;
      unsigned* o1 = (unsigned*)&w1;
#pragma unroll
      for (int i = 0; i < 4; ++i) {
        float lo = u2f(a0[i] << 16) + u2f(b0[i] << 16);
        float hi = u2f(a0[i] & 0xFFFF0000u) + u2f(b0[i] & 0xFFFF0000u);
        o0[i] = pack_rnd(lo * rin0, hi * rin0);
        lo = u2f(a1[i] << 16) + u2f(b1[i] << 16);
        hi = u2f(a1[i] & 0xFFFF0000u) + u2f(b1[i] & 0xFFFF0000u);
        o1[i] = pack_rnd(lo * rin1, hi * rin1);
      }
    }
    __syncthreads();
#if ASYNC_CP
    gl_lds16(Bp + k0, sBw);
    gl_lds16(Bp + k0 + (size_t)32 * K, sBw + 32 * 64);
    gl_lds16(Bp + k0 + (size_t)64 * K, sBw + 64 * 64);
    gl_lds16(Bp + k0 + (size_t)96 * K, sBw + 96 * 64);
#else
    {
      uint4 bv0 = *(const uint4*)(Bp + k0);
      uint4 bv1 = *(const uint4*)(Bp + k0 + (size_t)32 * K);
      uint4 bv2 = *(const uint4*)(Bp + k0 + (size_t)64 * K);
      uint4 bv3 = *(const uint4*)(Bp + k0 + (size_t)96 * K);
      *(uint4*)&sB[arow * 64 + achk] = bv0;
      *(uint4*)&sB[(arow + 32) * 64 + achk] = bv1;
      *(uint4*)&sB[(arow + 64) * 64 + achk] = bv2;
      *(uint4*)&sB[(arow + 96) * 64 + achk] = bv3;
    }
#endif
    *(uint4*)&sA[arow * 64 + achk] = w0;
    *(uint4*)&sA[(arow + 32) * 64 + achk] = w1;
    __syncthreads();

    // prefetch next iter's A partials + lsums (latency hides under MFMA)
    if (k0 < K - 64) {
      int h = (k0 >> 6) + 1;
      size_t o0 = (size_t)row0 * 1024 + h * 64 + achk;
      size_t o1 = (size_t)row1 * 1024 + h * 64 + achk;
      pa0 = *(const uint4*)(oP0 + o0);
      pb0 = *(const uint4*)(oP1 + o0);
      pa1 = *(const uint4*)(oP0 + o1);
      pb1 = *(const uint4*)(oP1 + o1);
      rin0 = 1.0f / (lP0[row0 * 16 + h] + lP1[row0 * 16 + h]);
      rin1 = 1.0f / (lP0[row1 * 16 + h] + lP1[row1 * 16 + h]);
    }

#pragma unroll
    for (int ks = 0; ks < 2; ++ks) {
      bf16x8 af[2], bf[4];
#pragma unroll
      for (int mi = 0; mi < 2; mi++)
        af[mi] = *(const bf16x8*)&sA[(wm * 32 + mi * 16 + l15) * 64 + ks * 32 + quad * 8];
#pragma unroll
      for (int ni = 0; ni < 4; ni++)
        bf[ni] = *(const bf16x8*)&sB[(wn * 64 + ni * 16 + l15) * 64 + ks * 32 + quad * 8];
#pragma unroll
      for (int mi = 0; mi < 2; mi++)
#pragma unroll
        for (int ni = 0; ni < 4; ni++)
          acc[mi][ni] = __builtin_amdgcn_mfma_f32_16x16x32_bf16(
              af[mi], bf[ni], acc[mi][ni], 0, 0, 0);
    }
  }
#pragma unroll
  for (int mi = 0; mi < 2; mi++)
#pragma unroll
    for (int ni = 0; ni < 4; ni++) {
      int row = m0 + wm * 32 + mi * 16 + quad * 4;
      int col = n0 + wn * 64 + ni * 16 + l15;
#pragma unroll
      for (int rr = 0; rr < 4; rr++)
        C[(size_t)(row + rr) * ldc + col] = acc[mi][ni][rr] + bias[col];
    }
}

// ---------------------------------------------------------------------------
extern "C" void kernel_launch(void* const* d_in, const int* in_sizes, int n_in,
                              void* d_out, int out_size, void* d_ws, size_t ws_size,
                              hipStream_t stream) {
  const float* x = (const float*)d_in[0];
  const float* gamma = (const float*)d_in[1];
  const float* beta = (const float*)d_in[2];
  const float* w_q = (const float*)d_in[3];
  const float* w_k = (const float*)d_in[4];
  const float* w_v = (const float*)d_in[5];
  const float* w_o = (const float*)d_in[6];
  const float* b_o = (const float*)d_in[7];
  float* out = (float*)d_out;

  // ws map (33 MB with overlays):
  //  [0,3)   wqkvT (dead after gemm1) -> lP0 @0, lP1 @256KB during attn
  //  [3,5)   woT   (live until gemm2)
  //  [5,13)  xn    (dead after gemm1) -> oP0 overlay
  //  [13,25) qkv   (live through attn)
  //  [25,33) oP1
  char* ws = (char*)d_ws;
  u16* wqkvT = (u16*)ws;
  float* lP0 = (float*)ws;
  float* lP1 = (float*)(ws + 256u * 1024);
  u16* woT = (u16*)(ws + 3u * 1024 * 1024);
  u16* xn = (u16*)(ws + 5u * 1024 * 1024);
  u16* oP0 = xn;
  u16* qkv = (u16*)(ws + 13u * 1024 * 1024);
  u16* oP1 = (u16*)(ws + 25u * 1024 * 1024);

  const float cexp = 0.125f * 1.44269504088896f;  // SCALE * log2(e)

  prep_kernel<<<4736, 256, 0, stream>>>(x, gamma, beta, xn, w_q, w_k, w_v, w_o,
                                        wqkvT, woT);

  gemm_qkv_kernel<<<dim3(12, 64), 256, 0, stream>>>(xn, wqkvT, qkv,
                                                    4096, 1536, 1024, 1536,
                                                    cexp, 1024);

  attn_kernel<<<dim3(8, 32, 2), 256, 0, stream>>>(qkv, oP0, oP1, lP0, lP1);

  gemm_o_kernel<<<dim3(8, 64), 256, 0, stream>>>(oP0, oP1, lP0, lP1,
                                                 woT, out, b_o);
}

// Round 8
// 180.829 us; speedup vs baseline: 1.0719x; 1.0719x over previous
//
#include <hip/hip_runtime.h>

typedef unsigned short u16;
typedef __bf16 bf16x8 __attribute__((ext_vector_type(8)));
typedef short s16x4 __attribute__((ext_vector_type(4)));
typedef float f32x4 __attribute__((ext_vector_type(4)));

__device__ __forceinline__ unsigned f2u(float f) { union { float f; unsigned u; } v; v.f = f; return v.u; }
__device__ __forceinline__ float u2f(unsigned u) { union { unsigned u; float f; } v; v.u = u; return v.f; }

__device__ __forceinline__ u16 f32_to_bf16(float f) {
  unsigned u = f2u(f);
  return (u16)((u + 0x7FFFu + ((u >> 16) & 1u)) >> 16);
}
__device__ __forceinline__ unsigned pack_rnd(float a, float b) {
  unsigned ra = f2u(a), rb = f2u(b);
  ra = ra + 0x7FFFu + ((ra >> 16) & 1u);
  rb = (rb + 0x7FFFu + ((rb >> 16) & 1u)) & 0xFFFF0000u;
  return (ra >> 16) | rb;
}
__device__ __forceinline__ unsigned pack_trunc(float a, float b) {
#if __has_builtin(__builtin_amdgcn_perm)
  return __builtin_amdgcn_perm(f2u(b), f2u(a), 0x07060302u);
#else
  return (f2u(a) >> 16) | (f2u(b) & 0xFFFF0000u);
#endif
}
__device__ __forceinline__ unsigned perm_lo(unsigned a, unsigned b) {
#if __has_builtin(__builtin_amdgcn_perm)
  return __builtin_amdgcn_perm(b, a, 0x05040100u);
#else
  return (a & 0xFFFFu) | (b << 16);
#endif
}
__device__ __forceinline__ unsigned perm_hi(unsigned a, unsigned b) {
#if __has_builtin(__builtin_amdgcn_perm)
  return __builtin_amdgcn_perm(b, a, 0x07060302u);
#else
  return (a >> 16) | (b & 0xFFFF0000u);
#endif
}

// async global->LDS, 16B per lane. LDS dest = wave-uniform base + lane*16.
#if __has_builtin(__builtin_amdgcn_global_load_lds)
#define ASYNC_CP 1
typedef __attribute__((address_space(1))) const unsigned gu32;
typedef __attribute__((address_space(3))) unsigned lu32;
__device__ __forceinline__ void gl_lds16(const u16* g, u16* l) {
  __builtin_amdgcn_global_load_lds((gu32*)g, (lu32*)l, 16, 0, 0);
}
#else
#define ASYNC_CP 0
#endif

// ---------------------------------------------------------------------------
// prep: blocks [0,4096) = LayerNorm rows; blocks [4096,4736) = weight
// transpose+cvt tiles (w_q 256, w_k 64, w_v 64, w_o 256).
// ---------------------------------------------------------------------------
__global__ __launch_bounds__(256) void prep_kernel(
    const float* __restrict__ x, const float* __restrict__ gamma,
    const float* __restrict__ beta, u16* __restrict__ xn,
    const float* __restrict__ w_q, const float* __restrict__ w_k,
    const float* __restrict__ w_v, const float* __restrict__ w_o,
    u16* __restrict__ wqkvT, u16* __restrict__ woT) {
  __shared__ float tile[64][65];
  int t = threadIdx.x;
  int bid = blockIdx.x;
  if (bid < 4096) {
    int row = bid;
    const float4 v = ((const float4*)(x + (size_t)row * 1024))[t];
    float s = v.x + v.y + v.z + v.w;
    float ss = v.x * v.x + v.y * v.y + v.z * v.z + v.w * v.w;
#pragma unroll
    for (int m = 1; m < 64; m <<= 1) {
      s += __shfl_xor(s, m, 64);
      ss += __shfl_xor(ss, m, 64);
    }
    __shared__ float as_[4], ass[4];
    int wave = t >> 6;
    if ((t & 63) == 0) { as_[wave] = s; ass[wave] = ss; }
    __syncthreads();
    s = as_[0] + as_[1] + as_[2] + as_[3];
    ss = ass[0] + ass[1] + ass[2] + ass[3];
    float mu = s * (1.0f / 1024.0f);
    float var = ss * (1.0f / 1024.0f) - mu * mu;
    float rstd = rsqrtf(var + 1e-5f);
    float4 g = ((const float4*)gamma)[t];
    float4 b = ((const float4*)beta)[t];
    uint2 o;
    o.x = pack_rnd((v.x - mu) * rstd * g.x + b.x, (v.y - mu) * rstd * g.y + b.y);
    o.y = pack_rnd((v.z - mu) * rstd * g.z + b.z, (v.w - mu) * rstd * g.w + b.w);
    ((uint2*)(xn + (size_t)row * 1024))[t] = o;
    return;
  }
  int idx = bid - 4096;
  const float* src; u16* dst; int N, n0, k0;
  if (idx < 256) {
    src = w_q; dst = wqkvT; N = 1024; n0 = (idx & 15) * 64; k0 = (idx >> 4) * 64;
  } else if (idx < 320) {
    int i = idx - 256;
    src = w_k; dst = wqkvT + 1024 * 1024; N = 256; n0 = (i & 3) * 64; k0 = (i >> 2) * 64;
  } else if (idx < 384) {
    int i = idx - 320;
    src = w_v; dst = wqkvT + 1280 * 1024; N = 256; n0 = (i & 3) * 64; k0 = (i >> 2) * 64;
  } else {
    int i = idx - 384;
    src = w_o; dst = woT; N = 1024; n0 = (i & 15) * 64; k0 = (i >> 4) * 64;
  }
  const int K = 1024;
  int c = t & 63, r4 = t >> 6;
#pragma unroll
  for (int rr = r4; rr < 64; rr += 4)
    tile[rr][c] = src[(size_t)(k0 + rr) * N + n0 + c];
  __syncthreads();
#pragma unroll
  for (int rr = r4; rr < 64; rr += 4)
    dst[(size_t)(n0 + rr) * K + k0 + c] = f32_to_bf16(tile[c][rr]);
}

// ---------------------------------------------------------------------------
// bf16 GEMM: C[M][N] = A[M][K] @ Bt[N][K]^T   (Bt pre-transposed, bf16)
// BM=64, BN=128, BK=64; 256 threads (4 waves 2x2), wave = 32x64 via 2x4 MFMA.
// OUT_MODE 0: bf16 store, cols<qcols scaled by qscale; 1: f32 store + bias.
// ---------------------------------------------------------------------------
template <int OUT_MODE>
__global__ __launch_bounds__(256) void gemm_bf16_k(
    const u16* __restrict__ A, const u16* __restrict__ Bt,
    void* __restrict__ Cv, const float* __restrict__ bias,
    int M, int N, int K, int ldc, float qscale, int qcols) {
  __shared__ __align__(16) u16 sA[64 * 64];
  __shared__ __align__(16) u16 sB[128 * 64];
  int t = threadIdx.x;
  int m0 = blockIdx.y * 64, n0 = blockIdx.x * 128;
  int wave = t >> 6, lane = t & 63;
  int wm = wave >> 1, wn = wave & 1;
  int l15 = lane & 15, quad = lane >> 4;

  f32x4 acc[2][4];
#pragma unroll
  for (int i = 0; i < 2; i++)
#pragma unroll
    for (int j = 0; j < 4; j++) acc[i][j] = f32x4{0.f, 0.f, 0.f, 0.f};

  int arow = wave * 8 + (lane >> 3);
  int achk = (lane & 7) * 8;
  const u16* Ap = A + (size_t)(m0 + arow) * K + achk;
  const u16* Bp = Bt + (size_t)(n0 + arow) * K + achk;
  u16* sAw = &sA[(wave * 8) * 64];
  u16* sBw = &sB[(wave * 8) * 64];

  for (int k0 = 0; k0 < K; k0 += 64) {
#if ASYNC_CP
    __syncthreads();
    gl_lds16(Ap + k0, sAw);
    gl_lds16(Ap + k0 + (size_t)32 * K, sAw + 32 * 64);
    gl_lds16(Bp + k0, sBw);
    gl_lds16(Bp + k0 + (size_t)32 * K, sBw + 32 * 64);
    gl_lds16(Bp + k0 + (size_t)64 * K, sBw + 64 * 64);
    gl_lds16(Bp + k0 + (size_t)96 * K, sBw + 96 * 64);
    __syncthreads();
#else
    uint4 av0 = *(const uint4*)(Ap + k0);
    uint4 av1 = *(const uint4*)(Ap + k0 + (size_t)32 * K);
    uint4 bv0 = *(const uint4*)(Bp + k0);
    uint4 bv1 = *(const uint4*)(Bp + k0 + (size_t)32 * K);
    uint4 bv2 = *(const uint4*)(Bp + k0 + (size_t)64 * K);
    uint4 bv3 = *(const uint4*)(Bp + k0 + (size_t)96 * K);
    __syncthreads();
    *(uint4*)&sA[arow * 64 + achk] = av0;
    *(uint4*)&sA[(arow + 32) * 64 + achk] = av1;
    *(uint4*)&sB[arow * 64 + achk] = bv0;
    *(uint4*)&sB[(arow + 32) * 64 + achk] = bv1;
    *(uint4*)&sB[(arow + 64) * 64 + achk] = bv2;
    *(uint4*)&sB[(arow + 96) * 64 + achk] = bv3;
    __syncthreads();
#endif
#pragma unroll
    for (int ks = 0; ks < 2; ++ks) {
      bf16x8 af[2], bf[4];
#pragma unroll
      for (int mi = 0; mi < 2; mi++)
        af[mi] = *(const bf16x8*)&sA[(wm * 32 + mi * 16 + l15) * 64 + ks * 32 + quad * 8];
#pragma unroll
      for (int ni = 0; ni < 4; ni++)
        bf[ni] = *(const bf16x8*)&sB[(wn * 64 + ni * 16 + l15) * 64 + ks * 32 + quad * 8];
#pragma unroll
      for (int mi = 0; mi < 2; mi++)
#pragma unroll
        for (int ni = 0; ni < 4; ni++)
          acc[mi][ni] = __builtin_amdgcn_mfma_f32_16x16x32_bf16(
              af[mi], bf[ni], acc[mi][ni], 0, 0, 0);
    }
  }
#pragma unroll
  for (int mi = 0; mi < 2; mi++)
#pragma unroll
    for (int ni = 0; ni < 4; ni++) {
      int row = m0 + wm * 32 + mi * 16 + quad * 4;
      int col = n0 + wn * 64 + ni * 16 + l15;
#pragma unroll
      for (int rr = 0; rr < 4; rr++) {
        float vv = acc[mi][ni][rr];
        if (OUT_MODE == 0) {
          float sc = (col < qcols) ? qscale : 1.0f;
          ((u16*)Cv)[(size_t)(row + rr) * ldc + col] = f32_to_bf16(vv * sc);
        } else {
          ((float*)Cv)[(size_t)(row + rr) * ldc + col] = vv + bias[col];
        }
      }
    }
}

// ---------------------------------------------------------------------------
// GQA flash attention v5: r4 structure + pi-permuted V enabling K=32 PV.
// Block = (qt: 256 q, bh, kz). 4 waves x 64 q; keys [kz*1024,+1024), tiles 64.
// S^T = K Q^T (16x16x32). P packed per ni into pb[qs][a] (a = ni-pair); V is
// staged with key-columns permuted by pi(k)=((k>>2)&3)*8+(k>>4)*4+(k&3) per
// 32-block so pb is a legal 16x16x32 B-operand. PV: 32 MFMA, lsum: 8 (K=32).
// Writes unnormalized O partial (bf16) + lsum (f32). Q pre-scaled in GEMM1.
// ---------------------------------------------------------------------------
__global__ __launch_bounds__(256) void attn_kernel(
    const u16* __restrict__ qkv, u16* __restrict__ oP0, u16* __restrict__ oP1,
    float* __restrict__ lP0, float* __restrict__ lP1) {
  const int LD = 1536;
  int qt = blockIdx.x;   // 0..7
  int bh = blockIdx.y;   // 0..31
  int kz = blockIdx.z;   // 0..1
  int b = bh >> 4, h = bh & 15, g = h >> 2;
  u16* oP = kz ? oP1 : oP0;
  float* lP = kz ? lP1 : lP0;

  __shared__ __align__(16) u16 sK[64 * 72];  // [key][d]
  __shared__ __align__(16) u16 sV[64 * 72];  // [d][pi-permuted key]

  int t = threadIdx.x, wave = t >> 6, lane = t & 63;
  int l15 = lane & 15, quad = lane >> 4;

  const u16* qbase = qkv + (size_t)(b * 2048 + qt * 256 + wave * 64) * LD + h * 64;
  const u16* kbase = qkv + (size_t)(b * 2048 + kz * 1024) * LD + 1024 + g * 64;
  const u16* vbase = kbase + 256;

  bf16x8 qf[4][2];
#pragma unroll
  for (int qs = 0; qs < 4; ++qs)
#pragma unroll
    for (int ks = 0; ks < 2; ++ks)
      qf[qs][ks] = *(const bf16x8*)(qbase + (size_t)(qs * 16 + l15) * LD + ks * 32 + quad * 8);

  f32x4 oacc[4][4];  // [qset][md]
  f32x4 lacc[4];     // [qset]
#pragma unroll
  for (int qs = 0; qs < 4; ++qs) {
    lacc[qs] = f32x4{0.f, 0.f, 0.f, 0.f};
#pragma unroll
    for (int md = 0; md < 4; ++md) oacc[qs][md] = f32x4{0.f, 0.f, 0.f, 0.f};
  }

  union { u16 s[8]; bf16x8 v; } vones;
#pragma unroll
  for (int i = 0; i < 8; ++i) vones.s[i] = 0x3F80;
  const f32x4 fzero = {0.f, 0.f, 0.f, 0.f};

  int sr = t >> 3, sq = t & 7;                  // K staging coords
  int vkp = (t & 31) * 2, vdc = (t >> 5) * 8;   // V staging: key pair, d-chunk
  // pi-permuted destination column for the key pair (pairs stay adjacent)
  int kap = vkp & 31;
  int vc = (vkp & ~31) | (((kap >> 2) & 3) * 8 + (kap >> 4) * 4 + (kap & 3));

  uint4 ka0, ka1, va0, va1;
  {
    const u16* kp0 = kbase + (size_t)sr * LD + sq * 8;
    ka0 = *(const uint4*)kp0;
    ka1 = *(const uint4*)(kp0 + (size_t)32 * LD);
    const u16* vp0 = vbase + (size_t)vkp * LD + vdc;
    va0 = *(const uint4*)vp0;
    va1 = *(const uint4*)(vp0 + LD);
  }

  for (int kt = 0; kt < 16; ++kt) {
    __syncthreads();
    *(uint4*)&sK[sr * 72 + sq * 8] = ka0;
    *(uint4*)&sK[(sr + 32) * 72 + sq * 8] = ka1;
    {
      const unsigned* aw = (const unsigned*)&va0;
      const unsigned* bw = (const unsigned*)&va1;
#pragma unroll
      for (int w = 0; w < 4; ++w) {
        *(unsigned*)&sV[(vdc + 2 * w) * 72 + vc] = perm_lo(aw[w], bw[w]);
        *(unsigned*)&sV[(vdc + 2 * w + 1) * 72 + vc] = perm_hi(aw[w], bw[w]);
      }
    }
    __syncthreads();

    if (kt < 15) {
      const u16* kp0 = kbase + (size_t)((kt + 1) * 64 + sr) * LD + sq * 8;
      ka0 = *(const uint4*)kp0;
      ka1 = *(const uint4*)(kp0 + (size_t)32 * LD);
      const u16* vp0 = vbase + (size_t)((kt + 1) * 64 + vkp) * LD + vdc;
      va0 = *(const uint4*)vp0;
      va1 = *(const uint4*)(vp0 + LD);
    }

#pragma unroll
    for (int a = 0; a < 2; ++a) {
      // QK^T + exp for the two ni tiles of this 32-key half; pack into pb
      union { unsigned u[4]; bf16x8 v; } pb[4];  // [qset]
#pragma unroll
      for (int ni2 = 0; ni2 < 2; ++ni2) {
        int ni = 2 * a + ni2;
        bf16x8 kf0 = *(const bf16x8*)&sK[(ni * 16 + l15) * 72 + quad * 8];
        bf16x8 kf1 = *(const bf16x8*)&sK[(ni * 16 + l15) * 72 + 32 + quad * 8];
        f32x4 sacc[4];
#pragma unroll
        for (int qs = 0; qs < 4; ++qs)
          sacc[qs] = __builtin_amdgcn_mfma_f32_16x16x32_bf16(kf0, qf[qs][0], fzero, 0, 0, 0);
#pragma unroll
        for (int qs = 0; qs < 4; ++qs)
          sacc[qs] = __builtin_amdgcn_mfma_f32_16x16x32_bf16(kf1, qf[qs][1], sacc[qs], 0, 0, 0);
#pragma unroll
        for (int qs = 0; qs < 4; ++qs) {
          float p0 = __builtin_amdgcn_exp2f(sacc[qs][0]);
          float p1 = __builtin_amdgcn_exp2f(sacc[qs][1]);
          float p2 = __builtin_amdgcn_exp2f(sacc[qs][2]);
          float p3 = __builtin_amdgcn_exp2f(sacc[qs][3]);
          pb[qs].u[2 * ni2] = pack_trunc(p0, p1);
          pb[qs].u[2 * ni2 + 1] = pack_trunc(p2, p3);
        }
      }
      // lsum += 1^T P^T (K=32) ; O^T += V^T P^T (K=32, pi-permuted V)
#pragma unroll
      for (int qs = 0; qs < 4; ++qs)
        lacc[qs] = __builtin_amdgcn_mfma_f32_16x16x32_bf16(vones.v, pb[qs].v, lacc[qs], 0, 0, 0);
#pragma unroll
      for (int md = 0; md < 4; ++md) {
        bf16x8 vf = *(const bf16x8*)&sV[(md * 16 + l15) * 72 + a * 32 + quad * 8];
#pragma unroll
        for (int qs = 0; qs < 4; ++qs)
          oacc[qs][md] = __builtin_amdgcn_mfma_f32_16x16x32_bf16(vf, pb[qs].v, oacc[qs][md], 0, 0, 0);
      }
    }
  }

  // epilogue: store unnormalized O partial (bf16 rounded) + lsum (f32)
#pragma unroll
  for (int qs = 0; qs < 4; ++qs) {
    int row = b * 2048 + qt * 256 + wave * 64 + qs * 16 + l15;
    u16* ob = oP + (size_t)row * 1024 + h * 64 + quad * 4;
#pragma unroll
    for (int md = 0; md < 4; ++md) {
      uint2 o;
      o.x = pack_rnd(oacc[qs][md][0], oacc[qs][md][1]);
      o.y = pack_rnd(oacc[qs][md][2], oacc[qs][md][3]);
      *(uint2*)(ob + md * 16) = o;
    }
    if (quad == 0) lP[row * 16 + h] = lacc[qs][0];
  }
}

// ---------------------------------------------------------------------------
// Combine: attn = (O0 + O1) / (l0 + l1), in place over oP1 (bf16 out).
// ---------------------------------------------------------------------------
__global__ __launch_bounds__(256) void attn_combine(
    const u16* __restrict__ oP0, u16* __restrict__ oP1_attn,
    const float* __restrict__ lP0, const float* __restrict__ lP1) {
  int t = threadIdx.x;
  int row = blockIdx.x * 2 + (t >> 7);
  int c8 = (t & 127) * 8;
  int h = c8 >> 6;
  float l = lP0[row * 16 + h] + lP1[row * 16 + h];
  float rinv = 1.0f / l;
  size_t off = (size_t)row * 1024 + c8;
  uint4 a = *(const uint4*)(oP0 + off);
  uint4 bb = *(const uint4*)(oP1_attn + off);
  const unsigned* aw = (const unsigned*)&a;
  const unsigned* bw = (const unsigned*)&bb;
  uint4 o;
  unsigned* ow = (unsigned*)&o;
#pragma unroll
  for (int i = 0; i < 4; ++i) {
    float x0 = u2f(aw[i] << 16) + u2f(bw[i] << 16);
    float x1 = u2f(aw[i] & 0xFFFF0000u) + u2f(bw[i] & 0xFFFF0000u);
    ow[i] = pack_rnd(x0 * rinv, x1 * rinv);
  }
  *(uint4*)(oP1_attn + off) = o;
}

// ---------------------------------------------------------------------------
extern "C" void kernel_launch(void* const* d_in, const int* in_sizes, int n_in,
                              void* d_out, int out_size, void* d_ws, size_t ws_size,
                              hipStream_t stream) {
  const float* x = (const float*)d_in[0];
  const float* gamma = (const float*)d_in[1];
  const float* beta = (const float*)d_in[2];
  const float* w_q = (const float*)d_in[3];
  const float* w_k = (const float*)d_in[4];
  const float* w_v = (const float*)d_in[5];
  const float* w_o = (const float*)d_in[6];
  const float* b_o = (const float*)d_in[7];
  float* out = (float*)d_out;

  // ws map (33 MB with overlays):
  //  [0,3)   wqkvT (dead after gemm1) -> lP0 @0, lP1 @256KB during attn
  //  [3,5)   woT   (live until gemm2)
  //  [5,13)  xn    (dead after gemm1) -> oP0 overlay
  //  [13,25) qkv   (live through attn)
  //  [25,33) oP1 / final attn (combine in place)
  char* ws = (char*)d_ws;
  u16* wqkvT = (u16*)ws;
  float* lP0 = (float*)ws;
  float* lP1 = (float*)(ws + 256u * 1024);
  u16* woT = (u16*)(ws + 3u * 1024 * 1024);
  u16* xn = (u16*)(ws + 5u * 1024 * 1024);
  u16* oP0 = xn;
  u16* qkv = (u16*)(ws + 13u * 1024 * 1024);
  u16* oP1 = (u16*)(ws + 25u * 1024 * 1024);

  const float cexp = 0.125f * 1.44269504088896f;  // SCALE * log2(e)

  prep_kernel<<<4736, 256, 0, stream>>>(x, gamma, beta, xn, w_q, w_k, w_v, w_o,
                                        wqkvT, woT);

  gemm_bf16_k<0><<<dim3(12, 64), 256, 0, stream>>>(xn, wqkvT, qkv, nullptr,
                                                   4096, 1536, 1024, 1536,
                                                   cexp, 1024);

  attn_kernel<<<dim3(8, 32, 2), 256, 0, stream>>>(qkv, oP0, oP1, lP0, lP1);
  attn_combine<<<dim3(2048), 256, 0, stream>>>(oP0, oP1, lP0, lP1);

  gemm_bf16_k<1><<<dim3(8, 64), 256, 0, stream>>>(oP1, woT, out, b_o,
                                                  4096, 1024, 1024, 1024,
                                                  1.0f, 0);
}

// Round 9
// 179.842 us; speedup vs baseline: 1.0778x; 1.0055x over previous
//
#include <hip/hip_runtime.h>

typedef unsigned short u16;
typedef __bf16 bf16x8 __attribute__((ext_vector_type(8)));
typedef short s16x4 __attribute__((ext_vector_type(4)));
typedef float f32x4 __attribute__((ext_vector_type(4)));

__device__ __forceinline__ unsigned f2u(float f) { union { float f; unsigned u; } v; v.f = f; return v.u; }
__device__ __forceinline__ float u2f(unsigned u) { union { unsigned u; float f; } v; v.u = u; return v.f; }

__device__ __forceinline__ u16 f32_to_bf16(float f) {
  unsigned u = f2u(f);
  return (u16)((u + 0x7FFFu + ((u >> 16) & 1u)) >> 16);
}
__device__ __forceinline__ unsigned pack_rnd(float a, float b) {
  unsigned ra = f2u(a), rb = f2u(b);
  ra = ra + 0x7FFFu + ((ra >> 16) & 1u);
  rb = (rb + 0x7FFFu + ((rb >> 16) & 1u)) & 0xFFFF0000u;
  return (ra >> 16) | rb;
}
__device__ __forceinline__ unsigned pack_trunc(float a, float b) {
#if __has_builtin(__builtin_amdgcn_perm)
  return __builtin_amdgcn_perm(f2u(b), f2u(a), 0x07060302u);
#else
  return (f2u(a) >> 16) | (f2u(b) & 0xFFFF0000u);
#endif
}
__device__ __forceinline__ unsigned perm_lo(unsigned a, unsigned b) {
#if __has_builtin(__builtin_amdgcn_perm)
  return __builtin_amdgcn_perm(b, a, 0x05040100u);
#else
  return (a & 0xFFFFu) | (b << 16);
#endif
}
__device__ __forceinline__ unsigned perm_hi(unsigned a, unsigned b) {
#if __has_builtin(__builtin_amdgcn_perm)
  return __builtin_amdgcn_perm(b, a, 0x07060302u);
#else
  return (a >> 16) | (b & 0xFFFF0000u);
#endif
}

// async global->LDS, 16B per lane. LDS dest = wave-uniform base + lane*16.
#if __has_builtin(__builtin_amdgcn_global_load_lds)
#define ASYNC_CP 1
typedef __attribute__((address_space(1))) const unsigned gu32;
typedef __attribute__((address_space(3))) unsigned lu32;
__device__ __forceinline__ void gl_lds16(const u16* g, u16* l) {
  __builtin_amdgcn_global_load_lds((gu32*)g, (lu32*)l, 16, 0, 0);
}
#else
#define ASYNC_CP 0
#endif

// ---------------------------------------------------------------------------
// prep: blocks [0,4096) = LayerNorm rows; blocks [4096,4736) = weight
// transpose+cvt tiles (w_q 256, w_k 64, w_v 64, w_o 256).
// ---------------------------------------------------------------------------
__global__ __launch_bounds__(256) void prep_kernel(
    const float* __restrict__ x, const float* __restrict__ gamma,
    const float* __restrict__ beta, u16* __restrict__ xn,
    const float* __restrict__ w_q, const float* __restrict__ w_k,
    const float* __restrict__ w_v, const float* __restrict__ w_o,
    u16* __restrict__ wqkvT, u16* __restrict__ woT) {
  __shared__ float tile[64][65];
  int t = threadIdx.x;
  int bid = blockIdx.x;
  if (bid < 4096) {
    int row = bid;
    const float4 v = ((const float4*)(x + (size_t)row * 1024))[t];
    float s = v.x + v.y + v.z + v.w;
    float ss = v.x * v.x + v.y * v.y + v.z * v.z + v.w * v.w;
#pragma unroll
    for (int m = 1; m < 64; m <<= 1) {
      s += __shfl_xor(s, m, 64);
      ss += __shfl_xor(ss, m, 64);
    }
    __shared__ float as_[4], ass[4];
    int wave = t >> 6;
    if ((t & 63) == 0) { as_[wave] = s; ass[wave] = ss; }
    __syncthreads();
    s = as_[0] + as_[1] + as_[2] + as_[3];
    ss = ass[0] + ass[1] + ass[2] + ass[3];
    float mu = s * (1.0f / 1024.0f);
    float var = ss * (1.0f / 1024.0f) - mu * mu;
    float rstd = rsqrtf(var + 1e-5f);
    float4 g = ((const float4*)gamma)[t];
    float4 b = ((const float4*)beta)[t];
    uint2 o;
    o.x = pack_rnd((v.x - mu) * rstd * g.x + b.x, (v.y - mu) * rstd * g.y + b.y);
    o.y = pack_rnd((v.z - mu) * rstd * g.z + b.z, (v.w - mu) * rstd * g.w + b.w);
    ((uint2*)(xn + (size_t)row * 1024))[t] = o;
    return;
  }
  int idx = bid - 4096;
  const float* src; u16* dst; int N, n0, k0;
  if (idx < 256) {
    src = w_q; dst = wqkvT; N = 1024; n0 = (idx & 15) * 64; k0 = (idx >> 4) * 64;
  } else if (idx < 320) {
    int i = idx - 256;
    src = w_k; dst = wqkvT + 1024 * 1024; N = 256; n0 = (i & 3) * 64; k0 = (i >> 2) * 64;
  } else if (idx < 384) {
    int i = idx - 320;
    src = w_v; dst = wqkvT + 1280 * 1024; N = 256; n0 = (i & 3) * 64; k0 = (i >> 2) * 64;
  } else {
    int i = idx - 384;
    src = w_o; dst = woT; N = 1024; n0 = (i & 15) * 64; k0 = (i >> 4) * 64;
  }
  const int K = 1024;
  int c = t & 63, r4 = t >> 6;
#pragma unroll
  for (int rr = r4; rr < 64; rr += 4)
    tile[rr][c] = src[(size_t)(k0 + rr) * N + n0 + c];
  __syncthreads();
#pragma unroll
  for (int rr = r4; rr < 64; rr += 4)
    dst[(size_t)(n0 + rr) * K + k0 + c] = f32_to_bf16(tile[c][rr]);
}

// ---------------------------------------------------------------------------
// bf16 GEMM: C[M][N] = A[M][K] @ Bt[N][K]^T   (Bt pre-transposed, bf16)
// BM=64, BN=128, BK=64; 256 threads (4 waves 2x2), wave = 32x64 via 2x4 MFMA.
// OUT_MODE 0: bf16 store, cols<qcols scaled by qscale; 1: f32 store + bias.
// ---------------------------------------------------------------------------
template <int OUT_MODE>
__global__ __launch_bounds__(256) void gemm_bf16_k(
    const u16* __restrict__ A, const u16* __restrict__ Bt,
    void* __restrict__ Cv, const float* __restrict__ bias,
    int M, int N, int K, int ldc, float qscale, int qcols) {
  __shared__ __align__(16) u16 sA[64 * 64];
  __shared__ __align__(16) u16 sB[128 * 64];
  int t = threadIdx.x;
  int m0 = blockIdx.y * 64, n0 = blockIdx.x * 128;
  int wave = t >> 6, lane = t & 63;
  int wm = wave >> 1, wn = wave & 1;
  int l15 = lane & 15, quad = lane >> 4;

  f32x4 acc[2][4];
#pragma unroll
  for (int i = 0; i < 2; i++)
#pragma unroll
    for (int j = 0; j < 4; j++) acc[i][j] = f32x4{0.f, 0.f, 0.f, 0.f};

  int arow = wave * 8 + (lane >> 3);
  int achk = (lane & 7) * 8;
  const u16* Ap = A + (size_t)(m0 + arow) * K + achk;
  const u16* Bp = Bt + (size_t)(n0 + arow) * K + achk;
  u16* sAw = &sA[(wave * 8) * 64];
  u16* sBw = &sB[(wave * 8) * 64];

  for (int k0 = 0; k0 < K; k0 += 64) {
#if ASYNC_CP
    __syncthreads();
    gl_lds16(Ap + k0, sAw);
    gl_lds16(Ap + k0 + (size_t)32 * K, sAw + 32 * 64);
    gl_lds16(Bp + k0, sBw);
    gl_lds16(Bp + k0 + (size_t)32 * K, sBw + 32 * 64);
    gl_lds16(Bp + k0 + (size_t)64 * K, sBw + 64 * 64);
    gl_lds16(Bp + k0 + (size_t)96 * K, sBw + 96 * 64);
    __syncthreads();
#else
    uint4 av0 = *(const uint4*)(Ap + k0);
    uint4 av1 = *(const uint4*)(Ap + k0 + (size_t)32 * K);
    uint4 bv0 = *(const uint4*)(Bp + k0);
    uint4 bv1 = *(const uint4*)(Bp + k0 + (size_t)32 * K);
    uint4 bv2 = *(const uint4*)(Bp + k0 + (size_t)64 * K);
    uint4 bv3 = *(const uint4*)(Bp + k0 + (size_t)96 * K);
    __syncthreads();
    *(uint4*)&sA[arow * 64 + achk] = av0;
    *(uint4*)&sA[(arow + 32) * 64 + achk] = av1;
    *(uint4*)&sB[arow * 64 + achk] = bv0;
    *(uint4*)&sB[(arow + 32) * 64 + achk] = bv1;
    *(uint4*)&sB[(arow + 64) * 64 + achk] = bv2;
    *(uint4*)&sB[(arow + 96) * 64 + achk] = bv3;
    __syncthreads();
#endif
#pragma unroll
    for (int ks = 0; ks < 2; ++ks) {
      bf16x8 af[2], bf[4];
#pragma unroll
      for (int mi = 0; mi < 2; mi++)
        af[mi] = *(const bf16x8*)&sA[(wm * 32 + mi * 16 + l15) * 64 + ks * 32 + quad * 8];
#pragma unroll
      for (int ni = 0; ni < 4; ni++)
        bf[ni] = *(const bf16x8*)&sB[(wn * 64 + ni * 16 + l15) * 64 + ks * 32 + quad * 8];
#pragma unroll
      for (int mi = 0; mi < 2; mi++)
#pragma unroll
        for (int ni = 0; ni < 4; ni++)
          acc[mi][ni] = __builtin_amdgcn_mfma_f32_16x16x32_bf16(
              af[mi], bf[ni], acc[mi][ni], 0, 0, 0);
    }
  }
#pragma unroll
  for (int mi = 0; mi < 2; mi++)
#pragma unroll
    for (int ni = 0; ni < 4; ni++) {
      int row = m0 + wm * 32 + mi * 16 + quad * 4;
      int col = n0 + wn * 64 + ni * 16 + l15;
#pragma unroll
      for (int rr = 0; rr < 4; rr++) {
        float vv = acc[mi][ni][rr];
        if (OUT_MODE == 0) {
          float sc = (col < qcols) ? qscale : 1.0f;
          ((u16*)Cv)[(size_t)(row + rr) * ldc + col] = f32_to_bf16(vv * sc);
        } else {
          ((float*)Cv)[(size_t)(row + rr) * ldc + col] = vv + bias[col];
        }
      }
    }
}

// ---------------------------------------------------------------------------
// GQA flash attention v6: v5 math (pi-permuted V, K=32 PV, ones-lsum) with
// 32 q/wave and doubled grid for 4 blocks/CU (4 waves/SIMD latency hiding).
// Block = (qt: 128 q, bh, kz); grid (16,32,2) = 1024 blocks.
// Writes unnormalized O partial (bf16) + lsum (f32). Q pre-scaled in GEMM1.
// ---------------------------------------------------------------------------
__global__ __launch_bounds__(256, 4) void attn_kernel(
    const u16* __restrict__ qkv, u16* __restrict__ oP0, u16* __restrict__ oP1,
    float* __restrict__ lP0, float* __restrict__ lP1) {
  const int LD = 1536;
  int qt = blockIdx.x;   // 0..15
  int bh = blockIdx.y;   // 0..31
  int kz = blockIdx.z;   // 0..1
  int b = bh >> 4, h = bh & 15, g = h >> 2;
  u16* oP = kz ? oP1 : oP0;
  float* lP = kz ? lP1 : lP0;

  __shared__ __align__(16) u16 sK[64 * 72];  // [key][d]
  __shared__ __align__(16) u16 sV[64 * 72];  // [d][pi-permuted key]

  int t = threadIdx.x, wave = t >> 6, lane = t & 63;
  int l15 = lane & 15, quad = lane >> 4;

  const u16* qbase = qkv + (size_t)(b * 2048 + qt * 128 + wave * 32) * LD + h * 64;
  const u16* kbase = qkv + (size_t)(b * 2048 + kz * 1024) * LD + 1024 + g * 64;
  const u16* vbase = kbase + 256;

  bf16x8 qf[2][2];
#pragma unroll
  for (int qs = 0; qs < 2; ++qs)
#pragma unroll
    for (int ks = 0; ks < 2; ++ks)
      qf[qs][ks] = *(const bf16x8*)(qbase + (size_t)(qs * 16 + l15) * LD + ks * 32 + quad * 8);

  f32x4 oacc[2][4];  // [qset][md]
  f32x4 lacc[2];     // [qset]
#pragma unroll
  for (int qs = 0; qs < 2; ++qs) {
    lacc[qs] = f32x4{0.f, 0.f, 0.f, 0.f};
#pragma unroll
    for (int md = 0; md < 4; ++md) oacc[qs][md] = f32x4{0.f, 0.f, 0.f, 0.f};
  }

  union { u16 s[8]; bf16x8 v; } vones;
#pragma unroll
  for (int i = 0; i < 8; ++i) vones.s[i] = 0x3F80;
  const f32x4 fzero = {0.f, 0.f, 0.f, 0.f};

  int sr = t >> 3, sq = t & 7;                  // K staging coords
  int vkp = (t & 31) * 2, vdc = (t >> 5) * 8;   // V staging: key pair, d-chunk
  // pi-permuted destination column for the key pair (pairs stay adjacent)
  int kap = vkp & 31;
  int vc = (vkp & ~31) | (((kap >> 2) & 3) * 8 + (kap >> 4) * 4 + (kap & 3));

  uint4 ka0, ka1, va0, va1;
  {
    const u16* kp0 = kbase + (size_t)sr * LD + sq * 8;
    ka0 = *(const uint4*)kp0;
    ka1 = *(const uint4*)(kp0 + (size_t)32 * LD);
    const u16* vp0 = vbase + (size_t)vkp * LD + vdc;
    va0 = *(const uint4*)vp0;
    va1 = *(const uint4*)(vp0 + LD);
  }

  for (int kt = 0; kt < 16; ++kt) {
    __syncthreads();
    *(uint4*)&sK[sr * 72 + sq * 8] = ka0;
    *(uint4*)&sK[(sr + 32) * 72 + sq * 8] = ka1;
    {
      const unsigned* aw = (const unsigned*)&va0;
      const unsigned* bw = (const unsigned*)&va1;
#pragma unroll
      for (int w = 0; w < 4; ++w) {
        *(unsigned*)&sV[(vdc + 2 * w) * 72 + vc] = perm_lo(aw[w], bw[w]);
        *(unsigned*)&sV[(vdc + 2 * w + 1) * 72 + vc] = perm_hi(aw[w], bw[w]);
      }
    }
    __syncthreads();

    if (kt < 15) {
      const u16* kp0 = kbase + (size_t)((kt + 1) * 64 + sr) * LD + sq * 8;
      ka0 = *(const uint4*)kp0;
      ka1 = *(const uint4*)(kp0 + (size_t)32 * LD);
      const u16* vp0 = vbase + (size_t)((kt + 1) * 64 + vkp) * LD + vdc;
      va0 = *(const uint4*)vp0;
      va1 = *(const uint4*)(vp0 + LD);
    }

#pragma unroll
    for (int a = 0; a < 2; ++a) {
      // QK^T + exp for the two ni tiles of this 32-key half; pack into pb
      union { unsigned u[4]; bf16x8 v; } pb[2];  // [qset]
#pragma unroll
      for (int ni2 = 0; ni2 < 2; ++ni2) {
        int ni = 2 * a + ni2;
        bf16x8 kf0 = *(const bf16x8*)&sK[(ni * 16 + l15) * 72 + quad * 8];
        bf16x8 kf1 = *(const bf16x8*)&sK[(ni * 16 + l15) * 72 + 32 + quad * 8];
        f32x4 sacc[2];
#pragma unroll
        for (int qs = 0; qs < 2; ++qs)
          sacc[qs] = __builtin_amdgcn_mfma_f32_16x16x32_bf16(kf0, qf[qs][0], fzero, 0, 0, 0);
#pragma unroll
        for (int qs = 0; qs < 2; ++qs)
          sacc[qs] = __builtin_amdgcn_mfma_f32_16x16x32_bf16(kf1, qf[qs][1], sacc[qs], 0, 0, 0);
#pragma unroll
        for (int qs = 0; qs < 2; ++qs) {
          float p0 = __builtin_amdgcn_exp2f(sacc[qs][0]);
          float p1 = __builtin_amdgcn_exp2f(sacc[qs][1]);
          float p2 = __builtin_amdgcn_exp2f(sacc[qs][2]);
          float p3 = __builtin_amdgcn_exp2f(sacc[qs][3]);
          pb[qs].u[2 * ni2] = pack_trunc(p0, p1);
          pb[qs].u[2 * ni2 + 1] = pack_trunc(p2, p3);
        }
      }
      // lsum += 1^T P^T (K=32) ; O^T += V^T P^T (K=32, pi-permuted V)
#pragma unroll
      for (int qs = 0; qs < 2; ++qs)
        lacc[qs] = __builtin_amdgcn_mfma_f32_16x16x32_bf16(vones.v, pb[qs].v, lacc[qs], 0, 0, 0);
#pragma unroll
      for (int md = 0; md < 4; ++md) {
        bf16x8 vf = *(const bf16x8*)&sV[(md * 16 + l15) * 72 + a * 32 + quad * 8];
#pragma unroll
        for (int qs = 0; qs < 2; ++qs)
          oacc[qs][md] = __builtin_amdgcn_mfma_f32_16x16x32_bf16(vf, pb[qs].v, oacc[qs][md], 0, 0, 0);
      }
    }
  }

  // epilogue: store unnormalized O partial (bf16 rounded) + lsum (f32)
#pragma unroll
  for (int qs = 0; qs < 2; ++qs) {
    int row = b * 2048 + qt * 128 + wave * 32 + qs * 16 + l15;
    u16* ob = oP + (size_t)row * 1024 + h * 64 + quad * 4;
#pragma unroll
    for (int md = 0; md < 4; ++md) {
      uint2 o;
      o.x = pack_rnd(oacc[qs][md][0], oacc[qs][md][1]);
      o.y = pack_rnd(oacc[qs][md][2], oacc[qs][md][3]);
      *(uint2*)(ob + md * 16) = o;
    }
    if (quad == 0) lP[row * 16 + h] = lacc[qs][0];
  }
}

// ---------------------------------------------------------------------------
// Combine: attn = (O0 + O1) / (l0 + l1), in place over oP1 (bf16 out).
// ---------------------------------------------------------------------------
__global__ __launch_bounds__(256) void attn_combine(
    const u16* __restrict__ oP0, u16* __restrict__ oP1_attn,
    const float* __restrict__ lP0, const float* __restrict__ lP1) {
  int t = threadIdx.x;
  int row = blockIdx.x * 2 + (t >> 7);
  int c8 = (t & 127) * 8;
  int h = c8 >> 6;
  float l = lP0[row * 16 + h] + lP1[row * 16 + h];
  float rinv = 1.0f / l;
  size_t off = (size_t)row * 1024 + c8;
  uint4 a = *(const uint4*)(oP0 + off);
  uint4 bb = *(const uint4*)(oP1_attn + off);
  const unsigned* aw = (const unsigned*)&a;
  const unsigned* bw = (const unsigned*)&bb;
  uint4 o;
  unsigned* ow = (unsigned*)&o;
#pragma unroll
  for (int i = 0; i < 4; ++i) {
    float x0 = u2f(aw[i] << 16) + u2f(bw[i] << 16);
    float x1 = u2f(aw[i] & 0xFFFF0000u) + u2f(bw[i] & 0xFFFF0000u);
    ow[i] = pack_rnd(x0 * rinv, x1 * rinv);
  }
  *(uint4*)(oP1_attn + off) = o;
}

// ---------------------------------------------------------------------------
extern "C" void kernel_launch(void* const* d_in, const int* in_sizes, int n_in,
                              void* d_out, int out_size, void* d_ws, size_t ws_size,
                              hipStream_t stream) {
  const float* x = (const float*)d_in[0];
  const float* gamma = (const float*)d_in[1];
  const float* beta = (const float*)d_in[2];
  const float* w_q = (const float*)d_in[3];
  const float* w_k = (const float*)d_in[4];
  const float* w_v = (const float*)d_in[5];
  const float* w_o = (const float*)d_in[6];
  const float* b_o = (const float*)d_in[7];
  float* out = (float*)d_out;

  // ws map (33 MB with overlays):
  //  [0,3)   wqkvT (dead after gemm1) -> lP0 @0, lP1 @256KB during attn
  //  [3,5)   woT   (live until gemm2)
  //  [5,13)  xn    (dead after gemm1) -> oP0 overlay
  //  [13,25) qkv   (live through attn)
  //  [25,33) oP1 / final attn (combine in place)
  char* ws = (char*)d_ws;
  u16* wqkvT = (u16*)ws;
  float* lP0 = (float*)ws;
  float* lP1 = (float*)(ws + 256u * 1024);
  u16* woT = (u16*)(ws + 3u * 1024 * 1024);
  u16* xn = (u16*)(ws + 5u * 1024 * 1024);
  u16* oP0 = xn;
  u16* qkv = (u16*)(ws + 13u * 1024 * 1024);
  u16* oP1 = (u16*)(ws + 25u * 1024 * 1024);

  const float cexp = 0.125f * 1.44269504088896f;  // SCALE * log2(e)

  prep_kernel<<<4736, 256, 0, stream>>>(x, gamma, beta, xn, w_q, w_k, w_v, w_o,
                                        wqkvT, woT);

  gemm_bf16_k<0><<<dim3(12, 64), 256, 0, stream>>>(xn, wqkvT, qkv, nullptr,
                                                   4096, 1536, 1024, 1536,
                                                   cexp, 1024);

  attn_kernel<<<dim3(16, 32, 2), 256, 0, stream>>>(qkv, oP0, oP1, lP0, lP1);
  attn_combine<<<dim3(2048), 256, 0, stream>>>(oP0, oP1, lP0, lP1);

  gemm_bf16_k<1><<<dim3(8, 64), 256, 0, stream>>>(oP1, woT, out, b_o,
                                                  4096, 1024, 1024, 1024,
                                                  1.0f, 0);
}